// Round 4
// baseline (316.803 us; speedup 1.0000x reference)
//
#include <hip/hip_runtime.h>
#include <stdint.h>
#include <math.h>

#define DMODEL 1280
#define NHEAD  20
#define DHEAD  64
#define NSEG   4
#define MAXS   1500
#define SPAD   1536              // padded per-segment kv length (multiple of 64)
#define TPAD   (NSEG*SPAD)       // 6144
#define QT256  ((MAXS + 255) / 256)  // 6 q-tiles for attention (256 q-rows/block)
#define BM 128
#define BN 128
#define BK 32
#define QSCALE 0.18033688011112042f  // 0.125 * log2(e): fold softmax scale+log2e into Q
#define NEGV  -1e30f

typedef float  f32x4  __attribute__((ext_vector_type(4)));
typedef __bf16 bf16x8 __attribute__((ext_vector_type(8)));

#if __has_builtin(__builtin_amdgcn_exp2f)
#define EXP2F(x) __builtin_amdgcn_exp2f(x)
#else
#define EXP2F(x) exp2f(x)
#endif

__device__ __forceinline__ ushort f2bf(float f) {
  union { float f; uint32_t u; } a; a.f = f;
  uint32_t u = a.u;
  u += 0x7FFFu + ((u >> 16) & 1u);   // RNE
  return (ushort)(u >> 16);
}

// async global->LDS, 16B per lane: lane i lands at lds + i*16 (wave-uniform base).
__device__ __forceinline__ void async16(const void* g, void* lds) {
  __builtin_amdgcn_global_load_lds((const __attribute__((address_space(1))) void*)g,
                                   (__attribute__((address_space(3))) void*)lds,
                                   16, 0, 0);
}

// kv permutation within each 32-block of the transposed-V layout:
// stored position p <-> actual offset a, p = ((a>>2)&3)*8 + ((a>>4)&1)*4 + (a&3)
__device__ __forceinline__ int perm32(int a) {
  return ((a >> 2) & 3) * 8 + ((a >> 4) & 1) * 4 + (a & 3);
}

// raw barrier (no vmcnt drain); memory clobbers pin LDS op order across it
#define GBAR()  do { asm volatile("" ::: "memory"); __builtin_amdgcn_s_barrier(); \
                     asm volatile("" ::: "memory"); } while (0)
#define WAITV(n) asm volatile("s_waitcnt vmcnt(" #n ")" ::: "memory")

// ---------------- fused fp32 -> bf16 convert: X then 4 weights (adjacent in ws) ----------
__global__ void __launch_bounds__(256)
cvt_all(const float* __restrict__ hs, const float* __restrict__ Wq,
        const float* __restrict__ Wk, const float* __restrict__ Wv,
        const float* __restrict__ Wo, ushort* __restrict__ dst, int nX, int DD) {
  const int i = (blockIdx.x * 256 + threadIdx.x) * 4;
  const float* src;
  if (i < nX) {
    src = hs + i;
  } else {
    int j = i - nX;
    const int z = (j >= DD) + (j >= 2 * DD) + (j >= 3 * DD);
    const float* w = (z == 0) ? Wq : (z == 1) ? Wk : (z == 2) ? Wv : Wo;
    src = w + (j - z * DD);
  }
  float4 v = *(const float4*)src;
  ushort4 o;
  o.x = f2bf(v.x); o.y = f2bf(v.y); o.z = f2bf(v.z); o.w = f2bf(v.w);
  *(ushort4*)(dst + i) = o;
}

// ---------------- 128x128 GEMM mainloop, depth-2 prefetch (3-buffer rotation) -----------
// C = A[M,K] * W[N,K]^T. LDS tile: 64 super-rows (2 K-rows) x 8 chunks of 16B,
// chunk pos p' = p ^ (sr&7); 128B super-rows + 3-bit XOR measured 0 bank conflicts.
// Pipeline per iter: [WAITV(own 4 loads of tile k) -> s_barrier -> stage tile k+2 into
// buf c-1 -> compute buf c]. WAITV precedes the barrier, so after the barrier EVERY
// wave's tile-k loads have landed (vmcnt is per-wave; barrier makes it collective).
// The stage into buf c-1 is safe: all waves finished reading it in iter k-1 (their
// MFMA lgkm waits complete before they reach this barrier). Loads get ~2 full
// iterations (>2000 cyc) to cover HBM latency; vmcnt never drains in steady state.
__device__ __forceinline__ void gemm_tile_mainloop(
    const ushort* __restrict__ A, const ushort* __restrict__ W,
    int M, int m0, int n0, ushort* As, ushort* Bs, f32x4 (&acc)[4][4])
{
  const int tid  = threadIdx.x;
  const int wave = tid >> 6, lane = tid & 63;
  const int quad = lane >> 4, c16 = lane & 15;
  const int wr = (wave >> 1) * 64, wc = (wave & 1) * 64;

  // staging slots: M0 = wave*128 + lane, M1 = M0 + 64 (512 slots/tile)
  const int M0 = wave * 128 + lane, M1 = M0 + 64;
  const int sr0 = M0 >> 3, pp0 = M0 & 7, p0 = pp0 ^ (sr0 & 7);
  const int sr1 = M1 >> 3, pp1 = M1 & 7, p1 = pp1 ^ (sr1 & 7);
  const int row0 = sr0 * 2 + (p0 >> 2), kc0 = (p0 & 3) << 3;
  const int row1 = sr1 * 2 + (p1 >> 2), kc1 = (p1 & 3) << 3;
  // no row clamp: OOB rows (m-edge tile) read into the next ws region; results masked at store
  const ushort* Ap0 = A + (size_t)(m0 + row0) * DMODEL + kc0;
  const ushort* Ap1 = A + (size_t)(m0 + row1) * DMODEL + kc1;
  const ushort* Bp0 = W + (size_t)(n0 + row0) * DMODEL + kc0;
  const ushort* Bp1 = W + (size_t)(n0 + row1) * DMODEL + kc1;
  const int o0 = wave * 1024;        // ushort offset of this wave's first 64 slots
  const int o1 = wave * 1024 + 512;
  const int BUF = BM * BK;           // 4096 ushorts per buffer

  // prologue: stage tiles k=0 (buf0) and k=32 (buf1); 8 loads in flight per wave
  async16(Ap0, As + o0); async16(Ap1, As + o1);
  async16(Bp0, Bs + o0); async16(Bp1, Bs + o1);
  async16(Ap0 + BK, As + BUF + o0); async16(Ap1 + BK, As + BUF + o1);
  async16(Bp0 + BK, Bs + BUF + o0); async16(Bp1 + BK, Bs + BUF + o1);

  int c = 0;
  for (int k0 = 0; k0 < DMODEL; k0 += BK) {
    if (k0 + BK < DMODEL) { WAITV(4); }   // retire tile k0's 4 loads, keep next 4 flying
    else                  { WAITV(0); }   // last iter: nothing else in flight
    GBAR();                               // collective: buf c ready; buf c-1 reads done
    const int kn = k0 + 2 * BK;
    if (kn < DMODEL) {                    // stage tile k0+64 into buf (c+2)%3 == c-1
      int c2 = c + 2; if (c2 >= 3) c2 -= 3;
      const int bo = c2 * BUF;
      async16(Ap0 + kn, As + bo + o0); async16(Ap1 + kn, As + bo + o1);
      async16(Bp0 + kn, Bs + bo + o0); async16(Bp1 + kn, Bs + bo + o1);
    }
    const ushort* Ab = As + c * BUF;
    const ushort* Bb = Bs + c * BUF;
    bf16x8 a[4], b[4];
#pragma unroll
    for (int i = 0; i < 4; ++i) {
      const int row = wr + i * 16 + c16;
      const int sr = row >> 1;
      const int off = (sr << 6) + (((((row & 1) << 2) | quad) ^ (sr & 7)) << 3);
      a[i] = *(const bf16x8*)(Ab + off);
    }
#pragma unroll
    for (int j = 0; j < 4; ++j) {
      const int row = wc + j * 16 + c16;
      const int sr = row >> 1;
      const int off = (sr << 6) + (((((row & 1) << 2) | quad) ^ (sr & 7)) << 3);
      b[j] = *(const bf16x8*)(Bb + off);
    }
#pragma unroll
    for (int i = 0; i < 4; ++i)
#pragma unroll
      for (int j = 0; j < 4; ++j)
        acc[i][j] = __builtin_amdgcn_mfma_f32_16x16x32_bf16(a[i], b[j], acc[i][j], 0, 0, 0);
    c = (c == 2) ? 0 : c + 1;
  }
}

// ---------------- projection GEMM (one z per dispatch, for per-kernel profiling) --------
// mode 0: Q (bias bq, pre-scaled by QSCALE) -> out[T,D]
// mode 1: K (no bias)                        -> out[T,D]
// mode 2: V (bias bv, transposed+permuted)   -> vt[D][NSEG][SPAD]
// grid (10, 47): x = n-tile, y = m-tile
__global__ void __launch_bounds__(256, 4)
gemm_proj(const ushort* __restrict__ X, const ushort* __restrict__ W,
          const float* __restrict__ bias, const int* __restrict__ cu,
          ushort* __restrict__ out, int M, int mode)
{
  __shared__ ushort As[3 * BM * BK], Bs[3 * BN * BK];   // 48 KB
  const int n0 = blockIdx.x * BN;
  const int m0 = blockIdx.y * BM;

  f32x4 acc[4][4];
  f32x4 zero = {0.f, 0.f, 0.f, 0.f};
#pragma unroll
  for (int i = 0; i < 4; ++i)
#pragma unroll
    for (int j = 0; j < 4; ++j) acc[i][j] = zero;

  gemm_tile_mainloop(X, W, M, m0, n0, As, Bs, acc);

  const int tid = threadIdx.x, wave = tid >> 6, lane = tid & 63;
  const int quad = lane >> 4, c16 = lane & 15;
  const int wr = (wave >> 1) * 64, wc = (wave & 1) * 64;

  if (mode == 2) {
    // V: write directly into transposed + kv-permuted layout vt[D][NSEG][SPAD]
    const int c1 = cu[1], c2 = cu[2], c3 = cu[3];
#pragma unroll
    for (int i = 0; i < 4; ++i) {
      const int t0 = m0 + wr + i * 16 + quad * 4;
      const int s0a = (t0 >= c1) + (t0 >= c2) + (t0 >= c3);
      const int s3a = (t0 + 3 >= c1) + (t0 + 3 >= c2) + (t0 + 3 >= c3);
      const int seg0 = (s0a == 0) ? 0 : (s0a == 1) ? c1 : (s0a == 2) ? c2 : c3;
#pragma unroll
      for (int j = 0; j < 4; ++j) {
        const int cfeat = n0 + wc + j * 16 + c16;
        const float bb = bias[cfeat];
        if (t0 + 3 < M && s0a == s3a) {
          const int s = t0 - seg0;                 // s ≡ t0 (mod 4): boundaries are mult of 4
          const size_t base = (size_t)cfeat * TPAD + (size_t)s0a * SPAD
                            + (size_t)(s & ~31) + perm32(s & 31);
          ushort4 w;
          w.x = f2bf(acc[i][j][0] + bb);
          w.y = f2bf(acc[i][j][1] + bb);
          w.z = f2bf(acc[i][j][2] + bb);
          w.w = f2bf(acc[i][j][3] + bb);
          *(ushort4*)(out + base) = w;
        } else {
#pragma unroll
          for (int r = 0; r < 4; ++r) {
            const int t = t0 + r;
            if (t < M) {
              const int sb = (t >= c1) + (t >= c2) + (t >= c3);
              const int sg = (sb == 0) ? 0 : (sb == 1) ? c1 : (sb == 2) ? c2 : c3;
              const int s = t - sg;
              out[(size_t)cfeat * TPAD + (size_t)sb * SPAD + (s & ~31) + perm32(s & 31)]
                  = f2bf(acc[i][j][r] + bb);
            }
          }
        }
      }
    }
  } else {
    const float oscale = (mode == 0) ? QSCALE : 1.0f;
#pragma unroll
    for (int i = 0; i < 4; ++i) {
      const int rbase = m0 + wr + i * 16 + quad * 4;
#pragma unroll
      for (int j = 0; j < 4; ++j) {
        const int c = n0 + wc + j * 16 + c16;
        const float bb = (mode == 0) ? bias[c] : 0.f;
#pragma unroll
        for (int r = 0; r < 4; ++r) {
          const int rr = rbase + r;
          if (rr < M) out[(size_t)rr * DMODEL + c] = f2bf((acc[i][j][r] + bb) * oscale);
        }
      }
    }
  }
}

// ---------------- output projection, fp32 out ----------------
// grid (10, 47): x = n-tile, y = m-tile
__global__ void __launch_bounds__(256, 4)
gemm_out(const ushort* __restrict__ A, const ushort* __restrict__ W,
         const float* __restrict__ bias, float* __restrict__ out, int M)
{
  __shared__ ushort As[3 * BM * BK], Bs[3 * BN * BK];   // 48 KB
  const int n0 = blockIdx.x * BN;
  const int m0 = blockIdx.y * BM;
  f32x4 acc[4][4];
  f32x4 zero = {0.f, 0.f, 0.f, 0.f};
#pragma unroll
  for (int i = 0; i < 4; ++i)
#pragma unroll
    for (int j = 0; j < 4; ++j) acc[i][j] = zero;

  gemm_tile_mainloop(A, W, M, m0, n0, As, Bs, acc);

  const int tid = threadIdx.x, wave = tid >> 6, lane = tid & 63;
  const int quad = lane >> 4, c16 = lane & 15;
  const int wr = (wave >> 1) * 64, wc = (wave & 1) * 64;
#pragma unroll
  for (int i = 0; i < 4; ++i) {
    const int rbase = m0 + wr + i * 16 + quad * 4;
#pragma unroll
    for (int j = 0; j < 4; ++j) {
      const int c = n0 + wc + j * 16 + c16;
      const float bb = bias[c];
#pragma unroll
      for (int r = 0; r < 4; ++r) {
        const int rr = rbase + r;
        if (rr < M) out[(size_t)rr * DMODEL + c] = acc[i][j][r] + bb;
      }
    }
  }
}

// ---------------- fused flash attention (8-wave, 256 q-rows/block) ----------------
// S^T trick (P stays in registers), no-max softmax, K/V double-buffer in LDS.
// LDS = 32 KB total: Q staged in all of it, then recycled as KV dbuf [2][8192 ushorts].
// grid: (NSEG*NHEAD, QT256): x = head-seg (pins all q-tiles of one (b,h) to one XCD)
__global__ void __launch_bounds__(512, 4)
attn_fused(const ushort* __restrict__ qb, const ushort* __restrict__ kb,
           const ushort* __restrict__ vt, ushort* __restrict__ ob,
           const int* __restrict__ cu, int T)
{
  __shared__ ushort SB[16384];     // 32 KB
  const int hs = blockIdx.x;
  const int b = hs / NHEAD, h = hs % NHEAD;
  const int seg0 = cu[b];
  const int len  = cu[b + 1] - seg0;
  const int q0 = blockIdx.y * 256;
  if (q0 >= len) return;
  const int tid = threadIdx.x, wave = tid >> 6, lane = tid & 63;
  const int quad = lane >> 4, c16 = lane & 15;

  // ---- stage Q (256 rows x 64 d = 32KB) into SB, pre-swizzled-global chunks ----
#pragma unroll
  for (int t = 0; t < 4; ++t) {
    const int slot = t * 512 + tid;
    const int r = slot >> 3, k2 = slot & 7;
    const int col = ((k2 ^ (r & 7)) << 3);
    async16(qb + (size_t)(seg0 + q0 + r) * DMODEL + h * DHEAD + col,
            &SB[(t * 512 + wave * 64) * 8]);
  }

  // ---- per-lane K/V staging pointers (512 threads cover 64 rows x 8 chunks) ----
  const int rK = tid >> 3, kK = tid & 7;
  const int colK = ((kK ^ (rK & 7)) << 3);
  const ushort* kp = kb + (size_t)(seg0 + rK) * DMODEL + h * DHEAD + colK;
  const ushort* vp = vt + (size_t)(h * DHEAD + rK) * TPAD + (size_t)b * SPAD + colK;
  const int ldsoff = wave * 512;   // ushort offset of this wave's 64 staging slots

  __syncthreads();   // Q published (drains vmcnt)

  // Q fragments -> registers; SB is dead afterwards (recycled as kv double-buffer)
  bf16x8 aq[2][2];
#pragma unroll
  for (int n = 0; n < 2; ++n)
#pragma unroll
    for (int ks = 0; ks < 2; ++ks) {
      const int row = wave * 32 + n * 16 + c16;
      aq[n][ks] = *(const bf16x8*)(&SB[row * 64 + (((ks * 4 + quad) ^ (c16 & 7)) << 3)]);
    }

  __syncthreads();   // all Q reads complete; SB reusable

  // stage kv tile 0 into buf0 (K at +0, V at +4096 within each 8192-ushort buffer)
  async16(kp, &SB[ldsoff]); async16(vp, &SB[4096 + ldsoff]);
  kp += (size_t)64 * DMODEL; vp += 64;

  float l_i[2] = {0.f, 0.f};
  f32x4 o_acc[2][4];
  f32x4 zero = {0.f, 0.f, 0.f, 0.f};
#pragma unroll
  for (int n = 0; n < 2; ++n)
#pragma unroll
    for (int m = 0; m < 4; ++m) o_acc[n][m] = zero;

  const int niter = (len + 63) >> 6;
  for (int it = 0; it < niter; ++it) {
    __syncthreads();   // publish buf it&1 (drains staging); prior-iter LDS reads done
    const ushort* Kt = &SB[(it & 1) * 8192];
    const ushort* Vt = Kt + 4096;

    // prefetch next kv-tile into the other buffer — overlaps this iteration's compute
    if (it + 1 < niter) {
      ushort* Dst = &SB[((it + 1) & 1) * 8192];
      async16(kp, Dst + ldsoff); async16(vp, Dst + 4096 + ldsoff);
      kp += (size_t)64 * DMODEL; vp += 64;
    }

    // S^T = K * Q^T : A = K-frag (m=kv), B = Q-frag (n=q). C: row(kv)=quad*4+reg, col(q)=c16
    f32x4 s[2][4];
    __builtin_amdgcn_s_setprio(1);
#pragma unroll
    for (int f = 0; f < 4; ++f) {
      const int row = f * 16 + c16;
      const int ch = c16 & 7;
      bf16x8 ak0 = *(const bf16x8*)(Kt + row * 64 + ((quad ^ ch) << 3));
      bf16x8 ak1 = *(const bf16x8*)(Kt + row * 64 + (((4 + quad) ^ ch) << 3));
#pragma unroll
      for (int n = 0; n < 2; ++n) {
        s[n][f] = zero;
        s[n][f] = __builtin_amdgcn_mfma_f32_16x16x32_bf16(ak0, aq[n][0], s[n][f], 0, 0, 0);
        s[n][f] = __builtin_amdgcn_mfma_f32_16x16x32_bf16(ak1, aq[n][1], s[n][f], 0, 0, 0);
      }
    }
    __builtin_amdgcn_s_setprio(0);

    // mask invalid kv (only last iteration; garbage K rows -> masked here)
    const int kv0 = it * 64;
    if (kv0 + 64 > len) {
#pragma unroll
      for (int f = 0; f < 4; ++f) {
        const int kvb = kv0 + f * 16 + quad * 4;
#pragma unroll
        for (int r = 0; r < 4; ++r)
          if (kvb + r >= len) { s[0][f][r] = NEGV; s[1][f][r] = NEGV; }
      }
    }

    // no-max softmax: p = exp2(s) directly (raw v_exp_f32; exp2(-1e30)=0 exactly);
    // per-lane partial l, cross-quad reduction deferred to epilogue
#pragma unroll
    for (int n = 0; n < 2; ++n) {
      float rs = 0.f;
#pragma unroll
      for (int f = 0; f < 4; ++f)
#pragma unroll
        for (int r = 0; r < 4; ++r) {
          const float p = EXP2F(s[n][f][r]);
          s[n][f][r] = p;
          rs += p;
        }
      l_i[n] += rs;
    }

    // pack P^T (registers) as B-operand: slot (quad,j) <-> kv = g*32 + (j>>2)*16 + quad*4 + (j&3)
    // compiler casts fuse to v_cvt_pk_bf16_f32 (m240: better than hand bit-packing)
    bf16x8 bp[2][2];
#pragma unroll
    for (int n = 0; n < 2; ++n)
#pragma unroll
      for (int g = 0; g < 2; ++g) {
        bf16x8 t;
#pragma unroll
        for (int r = 0; r < 4; ++r) {
          t[r]     = (__bf16)s[n][2 * g][r];
          t[r + 4] = (__bf16)s[n][2 * g + 1][r];
        }
        bp[n][g] = t;
      }

    // O^T += V^T * P^T : A = V^T-frag (m=d), B = P^T (regs). C: row(d)=quad*4+reg, col(q)=c16
    __builtin_amdgcn_s_setprio(1);
#pragma unroll
    for (int m = 0; m < 4; ++m) {
      const int row = m * 16 + c16;
      const int ch = c16 & 7;
      bf16x8 av0 = *(const bf16x8*)(Vt + row * 64 + ((quad ^ ch) << 3));
      bf16x8 av1 = *(const bf16x8*)(Vt + row * 64 + (((4 + quad) ^ ch) << 3));
#pragma unroll
      for (int n = 0; n < 2; ++n) {
        o_acc[n][m] = __builtin_amdgcn_mfma_f32_16x16x32_bf16(av0, bp[n][0], o_acc[n][m], 0, 0, 0);
        o_acc[n][m] = __builtin_amdgcn_mfma_f32_16x16x32_bf16(av1, bp[n][1], o_acc[n][m], 0, 0, 0);
      }
    }
    __builtin_amdgcn_s_setprio(0);
  }

  // epilogue: reduce l across quads, normalize, store bf16.
  // O^T: d = m*16+quad*4+r, q = wave*32+n*16+c16
#pragma unroll
  for (int n = 0; n < 2; ++n) {
    float l = l_i[n];
    l += __shfl_xor(l, 16);
    l += __shfl_xor(l, 32);
    const int q = q0 + wave * 32 + n * 16 + c16;
    if (q < len) {
      const float inv = 1.0f / l;
      const size_t base = (size_t)(seg0 + q) * DMODEL + h * DHEAD;
#pragma unroll
      for (int m = 0; m < 4; ++m) {
        ushort4 pk;
        pk.x = f2bf(o_acc[n][m][0] * inv);
        pk.y = f2bf(o_acc[n][m][1] * inv);
        pk.z = f2bf(o_acc[n][m][2] * inv);
        pk.w = f2bf(o_acc[n][m][3] * inv);
        *(ushort4*)(ob + base + m * 16 + quad * 4) = pk;
      }
    }
  }
}

// ---------------- launch ----------------
extern "C" void kernel_launch(void* const* d_in, const int* in_sizes, int n_in,
                              void* d_out, int out_size, void* d_ws, size_t ws_size,
                              hipStream_t stream)
{
  (void)n_in; (void)out_size; (void)ws_size;
  const float* hs = (const float*)d_in[0];
  const int*   cu = (const int*)d_in[1];
  const float* Wq = (const float*)d_in[2];
  const float* bq = (const float*)d_in[3];
  const float* Wk = (const float*)d_in[4];
  const float* Wv = (const float*)d_in[5];
  const float* bv = (const float*)d_in[6];
  const float* Wo = (const float*)d_in[7];
  const float* bo = (const float*)d_in[8];
  float* out = (float*)d_out;
  const int T  = in_sizes[0] / DMODEL;            // 6000
  const int DD = DMODEL * DMODEL;
  const int nX = T * DMODEL;

  // workspace layout (ushort elements):
  //   [0]      X bf16 [T,D]   (reused as ob after projections)
  //   [nX]     W4 bf16 [4][D,D]
  //   [+4DD]   qb [T,D]
  //   [+T*D]   kb [T,D]
  //   [+T*D]   vt [D][NSEG][SPAD]   (last region: attn OOB row reads stay inside ws)
  ushort* ws  = (ushort*)d_ws;
  ushort* X   = ws;
  ushort* W4  = X + (size_t)nX;
  ushort* qb  = W4 + 4 * (size_t)DD;
  ushort* kb  = qb + (size_t)T * DMODEL;
  ushort* vt  = kb + (size_t)T * DMODEL;
  ushort* ob  = X;                                // X dead after projections

  const int ncvt = nX + 4 * DD;
  cvt_all<<<(ncvt / 4 + 255) / 256, 256, 0, stream>>>(hs, Wq, Wk, Wv, Wo, ws, nX, DD);

  const dim3 gproj(10, (T + BM - 1) / BM);
  gemm_proj<<<gproj, 256, 0, stream>>>(X, W4,                    bq, cu, qb, T, 0);
  gemm_proj<<<gproj, 256, 0, stream>>>(X, W4 + (size_t)DD,  nullptr, cu, kb, T, 1);
  gemm_proj<<<gproj, 256, 0, stream>>>(X, W4 + 2 * (size_t)DD,   bv, cu, vt, T, 2);

  attn_fused<<<dim3(NSEG * NHEAD, QT256), 512, 0, stream>>>(qb, kb, vt, ob, cu, T);

  gemm_out<<<gproj, 256, 0, stream>>>(ob, W4 + 3 * (size_t)DD, bo, out, T);
}

// Round 5
// 297.764 us; speedup vs baseline: 1.0639x; 1.0639x over previous
//
#include <hip/hip_runtime.h>
#include <stdint.h>
#include <math.h>

#define DMODEL 1280
#define NHEAD  20
#define DHEAD  64
#define NSEG   4
#define MAXS   1500
#define SPAD   1536              // padded per-segment kv length (multiple of 64)
#define TPAD   (NSEG*SPAD)       // 6144
#define QT256  ((MAXS + 255) / 256)  // 6 q-tiles for attention (256 q-rows/block)
#define BM 128
#define BN 128
#define BK 32
#define QSCALE 0.18033688011112042f  // 0.125 * log2(e): fold softmax scale+log2e into Q
#define NEGV  -1e30f

typedef float  f32x4  __attribute__((ext_vector_type(4)));
typedef __bf16 bf16x8 __attribute__((ext_vector_type(8)));

#if __has_builtin(__builtin_amdgcn_exp2f)
#define EXP2F(x) __builtin_amdgcn_exp2f(x)
#else
#define EXP2F(x) exp2f(x)
#endif

__device__ __forceinline__ ushort f2bf(float f) {
  union { float f; uint32_t u; } a; a.f = f;
  uint32_t u = a.u;
  u += 0x7FFFu + ((u >> 16) & 1u);   // RNE
  return (ushort)(u >> 16);
}

// async global->LDS, 16B per lane: lane i lands at lds + i*16 (wave-uniform base).
__device__ __forceinline__ void async16(const void* g, void* lds) {
  __builtin_amdgcn_global_load_lds((const __attribute__((address_space(1))) void*)g,
                                   (__attribute__((address_space(3))) void*)lds,
                                   16, 0, 0);
}

// kv permutation within each 32-block of the transposed-V layout:
// stored position p <-> actual offset a, p = ((a>>2)&3)*8 + ((a>>4)&1)*4 + (a&3)
__device__ __forceinline__ int perm32(int a) {
  return ((a >> 2) & 3) * 8 + ((a >> 4) & 1) * 4 + (a & 3);
}

// ---------------- fused fp32 -> bf16 convert: X then 4 weights (adjacent in ws) ----------
__global__ void __launch_bounds__(256)
cvt_all(const float* __restrict__ hs, const float* __restrict__ Wq,
        const float* __restrict__ Wk, const float* __restrict__ Wv,
        const float* __restrict__ Wo, ushort* __restrict__ dst, int nX, int DD) {
  const int i = (blockIdx.x * 256 + threadIdx.x) * 4;
  const float* src;
  if (i < nX) {
    src = hs + i;
  } else {
    int j = i - nX;
    const int z = (j >= DD) + (j >= 2 * DD) + (j >= 3 * DD);
    const float* w = (z == 0) ? Wq : (z == 1) ? Wk : (z == 2) ? Wv : Wo;
    src = w + (j - z * DD);
  }
  float4 v = *(const float4*)src;
  ushort4 o;
  o.x = f2bf(v.x); o.y = f2bf(v.y); o.z = f2bf(v.z); o.w = f2bf(v.w);
  *(ushort4*)(dst + i) = o;
}

// ---------------- GEMM mainloop (C = A[M,K] * W[N,K]^T) ----------------
// (R2-proven structure: 128x128 tile, 2-buffer global_load_lds, ~2.3 blocks/CU)
// LDS tile: 64 super-rows (2 K-rows) x 8 chunks of 16B, chunk pos p' = p ^ (sr&7);
// 128B super-rows + 3-bit XOR measured 0 bank conflicts.
__device__ __forceinline__ void gemm_tile_mainloop(
    const ushort* __restrict__ A, const ushort* __restrict__ W,
    int M, int m0, int n0, ushort* As, ushort* Bs, f32x4 (&acc)[4][4])
{
  const int tid  = threadIdx.x;
  const int wave = tid >> 6, lane = tid & 63;
  const int quad = lane >> 4, c16 = lane & 15;
  const int wr = (wave >> 1) * 64, wc = (wave & 1) * 64;

  // staging slots: M0 = wave*128 + lane, M1 = M0 + 64 (512 slots/tile)
  const int M0 = wave * 128 + lane, M1 = M0 + 64;
  const int sr0 = M0 >> 3, pp0 = M0 & 7, p0 = pp0 ^ (sr0 & 7);
  const int sr1 = M1 >> 3, pp1 = M1 & 7, p1 = pp1 ^ (sr1 & 7);
  const int row0 = sr0 * 2 + (p0 >> 2), kc0 = (p0 & 3) << 3;
  const int row1 = sr1 * 2 + (p1 >> 2), kc1 = (p1 & 3) << 3;
  // no row clamp: OOB rows (m-edge tile) read into the next ws region; results masked at store
  const ushort* Ap0 = A + (size_t)(m0 + row0) * DMODEL + kc0;
  const ushort* Ap1 = A + (size_t)(m0 + row1) * DMODEL + kc1;
  const ushort* Bp0 = W + (size_t)(n0 + row0) * DMODEL + kc0;
  const ushort* Bp1 = W + (size_t)(n0 + row1) * DMODEL + kc1;
  const int o0 = wave * 1024;        // ushort offset of this wave's first 64 slots
  const int o1 = wave * 1024 + 512;
  const int BUF = BM * BK;           // 4096 ushorts per buffer

  // prologue: stage k0 = 0 into buffer 0
  async16(Ap0, As + o0); async16(Ap1, As + o1);
  async16(Bp0, Bs + o0); async16(Bp1, Bs + o1);

  int c = 0;
  for (int k0 = 0; k0 < DMODEL; k0 += BK, c ^= 1) {
    __syncthreads();                 // publishes buf c (drains the staging loads)
    if (k0 + BK < DMODEL) {          // prefetch next tile into buf c^1 (overlaps compute)
      const int kn = k0 + BK;
      const int bo = (c ^ 1) * BUF;
      async16(Ap0 + kn, As + bo + o0); async16(Ap1 + kn, As + bo + o1);
      async16(Bp0 + kn, Bs + bo + o0); async16(Bp1 + kn, Bs + bo + o1);
    }
    const ushort* Ab = As + c * BUF;
    const ushort* Bb = Bs + c * BUF;
    bf16x8 a[4], b[4];
#pragma unroll
    for (int i = 0; i < 4; ++i) {
      const int row = wr + i * 16 + c16;
      const int sr = row >> 1;
      const int off = (sr << 6) + (((((row & 1) << 2) | quad) ^ (sr & 7)) << 3);
      a[i] = *(const bf16x8*)(Ab + off);
    }
#pragma unroll
    for (int j = 0; j < 4; ++j) {
      const int row = wc + j * 16 + c16;
      const int sr = row >> 1;
      const int off = (sr << 6) + (((((row & 1) << 2) | quad) ^ (sr & 7)) << 3);
      b[j] = *(const bf16x8*)(Bb + off);
    }
#pragma unroll
    for (int i = 0; i < 4; ++i)
#pragma unroll
      for (int j = 0; j < 4; ++j)
        acc[i][j] = __builtin_amdgcn_mfma_f32_16x16x32_bf16(a[i], b[j], acc[i][j], 0, 0, 0);
  }
}

// ---------------- fused QKV projection, bf16 out (Q pre-scaled, V written transposed) ------
// grid (32, 47): x = weight-group (z*10 + ntile; stride-8 XCD pinning), y = m-tile
// FUSED (not per-z split): R4 attribution showed split costs ~+68 us (3x57 vs 103 fused)
// -- X-panel L2 reuse across z + full-grid occupancy dominate.
__global__ void __launch_bounds__(256, 4)
gemm_qkv(const ushort* __restrict__ X, const ushort* __restrict__ W4,
         const float* __restrict__ bq, const float* __restrict__ bv,
         const int* __restrict__ cu,
         ushort* __restrict__ qb, ushort* __restrict__ kb, ushort* __restrict__ vt, int M)
{
  __shared__ ushort As[2 * BM * BK], Bs[2 * BN * BK];
  const int wg = blockIdx.x;
  if (wg >= 30) return;
  const int z = wg / 10;
  const int n0 = (wg % 10) * BN;
  const int m0 = blockIdx.y * BM;
  const ushort* W = W4 + (size_t)z * DMODEL * DMODEL;

  f32x4 acc[4][4];
  f32x4 zero = {0.f, 0.f, 0.f, 0.f};
#pragma unroll
  for (int i = 0; i < 4; ++i)
#pragma unroll
    for (int j = 0; j < 4; ++j) acc[i][j] = zero;

  gemm_tile_mainloop(X, W, M, m0, n0, As, Bs, acc);

  const int tid = threadIdx.x, wave = tid >> 6, lane = tid & 63;
  const int quad = lane >> 4, c16 = lane & 15;
  const int wr = (wave >> 1) * 64, wc = (wave & 1) * 64;

  if (z == 2) {
    // V: write directly into transposed + kv-permuted layout vt[D][NSEG][SPAD]
    const int c1 = cu[1], c2 = cu[2], c3 = cu[3];
#pragma unroll
    for (int i = 0; i < 4; ++i) {
      const int t0 = m0 + wr + i * 16 + quad * 4;
      const int s0a = (t0 >= c1) + (t0 >= c2) + (t0 >= c3);
      const int s3a = (t0 + 3 >= c1) + (t0 + 3 >= c2) + (t0 + 3 >= c3);
      const int seg0 = (s0a == 0) ? 0 : (s0a == 1) ? c1 : (s0a == 2) ? c2 : c3;
#pragma unroll
      for (int j = 0; j < 4; ++j) {
        const int cfeat = n0 + wc + j * 16 + c16;
        const float bb = bv[cfeat];
        if (t0 + 3 < M && s0a == s3a) {
          const int s = t0 - seg0;                 // s ≡ t0 (mod 4): boundaries are mult of 4
          const size_t base = (size_t)cfeat * TPAD + (size_t)s0a * SPAD
                            + (size_t)(s & ~31) + perm32(s & 31);
          ushort4 w;
          w.x = f2bf(acc[i][j][0] + bb);
          w.y = f2bf(acc[i][j][1] + bb);
          w.z = f2bf(acc[i][j][2] + bb);
          w.w = f2bf(acc[i][j][3] + bb);
          *(ushort4*)(vt + base) = w;
        } else {
#pragma unroll
          for (int r = 0; r < 4; ++r) {
            const int t = t0 + r;
            if (t < M) {
              const int sb = (t >= c1) + (t >= c2) + (t >= c3);
              const int sg = (sb == 0) ? 0 : (sb == 1) ? c1 : (sb == 2) ? c2 : c3;
              const int s = t - sg;
              vt[(size_t)cfeat * TPAD + (size_t)sb * SPAD + (s & ~31) + perm32(s & 31)]
                  = f2bf(acc[i][j][r] + bb);
            }
          }
        }
      }
    }
  } else {
    ushort* out = (z == 0) ? qb : kb;
    const float* bias = (z == 0) ? bq : (const float*)nullptr;
    const float oscale = (z == 0) ? QSCALE : 1.0f;
#pragma unroll
    for (int i = 0; i < 4; ++i) {
      const int rbase = m0 + wr + i * 16 + quad * 4;
#pragma unroll
      for (int j = 0; j < 4; ++j) {
        const int c = n0 + wc + j * 16 + c16;
        const float bb = bias ? bias[c] : 0.f;
#pragma unroll
        for (int r = 0; r < 4; ++r) {
          const int rr = rbase + r;
          if (rr < M) out[(size_t)rr * DMODEL + c] = f2bf((acc[i][j][r] + bb) * oscale);
        }
      }
    }
  }
}

// ---------------- output projection, fp32 out ----------------
// grid (16, 47): x = n-tile (padded to 16 for XCD pinning), y = m-tile
__global__ void __launch_bounds__(256, 4)
gemm_out(const ushort* __restrict__ A, const ushort* __restrict__ W,
         const float* __restrict__ bias, float* __restrict__ out, int M)
{
  __shared__ ushort As[2 * BM * BK], Bs[2 * BN * BK];
  const int wg = blockIdx.x;
  if (wg >= 10) return;
  const int n0 = wg * BN;
  const int m0 = blockIdx.y * BM;
  f32x4 acc[4][4];
  f32x4 zero = {0.f, 0.f, 0.f, 0.f};
#pragma unroll
  for (int i = 0; i < 4; ++i)
#pragma unroll
    for (int j = 0; j < 4; ++j) acc[i][j] = zero;

  gemm_tile_mainloop(A, W, M, m0, n0, As, Bs, acc);

  const int tid = threadIdx.x, wave = tid >> 6, lane = tid & 63;
  const int quad = lane >> 4, c16 = lane & 15;
  const int wr = (wave >> 1) * 64, wc = (wave & 1) * 64;
#pragma unroll
  for (int i = 0; i < 4; ++i) {
    const int rbase = m0 + wr + i * 16 + quad * 4;
#pragma unroll
    for (int j = 0; j < 4; ++j) {
      const int c = n0 + wc + j * 16 + c16;
      const float bb = bias[c];
#pragma unroll
      for (int r = 0; r < 4; ++r) {
        const int rr = rbase + r;
        if (rr < M) out[(size_t)rr * DMODEL + c] = acc[i][j][r] + bb;
      }
    }
  }
}

// ---------------- fused flash attention (8-wave, 256 q-rows/block) ----------------
// S^T trick (P stays in registers), no-max softmax, K/V double-buffer in LDS.
// P->bf16 via compiler casts (fuse to v_cvt_pk_bf16_f32): R3->R4 attribution shows this
// halved attn vs the manual pk2 bit-pack (~115 -> 58.5 us) -- keep, do not hand-pack.
// LDS = 32 KB total: Q staged in all of it, then recycled as KV dbuf [2][8192 ushorts].
// grid: (NSEG*NHEAD, QT256): x = head-seg (pins all q-tiles of one (b,h) to one XCD)
__global__ void __launch_bounds__(512, 4)
attn_fused(const ushort* __restrict__ qb, const ushort* __restrict__ kb,
           const ushort* __restrict__ vt, ushort* __restrict__ ob,
           const int* __restrict__ cu, int T)
{
  __shared__ ushort SB[16384];     // 32 KB
  const int hs = blockIdx.x;
  const int b = hs / NHEAD, h = hs % NHEAD;
  const int seg0 = cu[b];
  const int len  = cu[b + 1] - seg0;
  const int q0 = blockIdx.y * 256;
  if (q0 >= len) return;
  const int tid = threadIdx.x, wave = tid >> 6, lane = tid & 63;
  const int quad = lane >> 4, c16 = lane & 15;

  // ---- stage Q (256 rows x 64 d = 32KB) into SB, pre-swizzled-global chunks ----
#pragma unroll
  for (int t = 0; t < 4; ++t) {
    const int slot = t * 512 + tid;
    const int r = slot >> 3, k2 = slot & 7;
    const int col = ((k2 ^ (r & 7)) << 3);
    async16(qb + (size_t)(seg0 + q0 + r) * DMODEL + h * DHEAD + col,
            &SB[(t * 512 + wave * 64) * 8]);
  }

  // ---- per-lane K/V staging pointers (512 threads cover 64 rows x 8 chunks) ----
  const int rK = tid >> 3, kK = tid & 7;
  const int colK = ((kK ^ (rK & 7)) << 3);
  const ushort* kp = kb + (size_t)(seg0 + rK) * DMODEL + h * DHEAD + colK;
  const ushort* vp = vt + (size_t)(h * DHEAD + rK) * TPAD + (size_t)b * SPAD + colK;
  const int ldsoff = wave * 512;   // ushort offset of this wave's 64 staging slots

  __syncthreads();   // Q published (drains vmcnt)

  // Q fragments -> registers; SB is dead afterwards (recycled as kv double-buffer)
  bf16x8 aq[2][2];
#pragma unroll
  for (int n = 0; n < 2; ++n)
#pragma unroll
    for (int ks = 0; ks < 2; ++ks) {
      const int row = wave * 32 + n * 16 + c16;
      aq[n][ks] = *(const bf16x8*)(&SB[row * 64 + (((ks * 4 + quad) ^ (c16 & 7)) << 3)]);
    }

  __syncthreads();   // all Q reads complete; SB reusable

  // stage kv tile 0 into buf0 (K at +0, V at +4096 within each 8192-ushort buffer)
  async16(kp, &SB[ldsoff]); async16(vp, &SB[4096 + ldsoff]);
  kp += (size_t)64 * DMODEL; vp += 64;

  float l_i[2] = {0.f, 0.f};
  f32x4 o_acc[2][4];
  f32x4 zero = {0.f, 0.f, 0.f, 0.f};
#pragma unroll
  for (int n = 0; n < 2; ++n)
#pragma unroll
    for (int m = 0; m < 4; ++m) o_acc[n][m] = zero;

  const int niter = (len + 63) >> 6;
  for (int it = 0; it < niter; ++it) {
    __syncthreads();   // publish buf it&1 (drains staging); prior-iter LDS reads done
    const ushort* Kt = &SB[(it & 1) * 8192];
    const ushort* Vt = Kt + 4096;

    // prefetch next kv-tile into the other buffer — overlaps this iteration's compute
    if (it + 1 < niter) {
      ushort* Dst = &SB[((it + 1) & 1) * 8192];
      async16(kp, Dst + ldsoff); async16(vp, Dst + 4096 + ldsoff);
      kp += (size_t)64 * DMODEL; vp += 64;
    }

    // S^T = K * Q^T : A = K-frag (m=kv), B = Q-frag (n=q). C: row(kv)=quad*4+reg, col(q)=c16
    f32x4 s[2][4];
    __builtin_amdgcn_s_setprio(1);
#pragma unroll
    for (int f = 0; f < 4; ++f) {
      const int row = f * 16 + c16;
      const int ch = c16 & 7;
      bf16x8 ak0 = *(const bf16x8*)(Kt + row * 64 + ((quad ^ ch) << 3));
      bf16x8 ak1 = *(const bf16x8*)(Kt + row * 64 + (((4 + quad) ^ ch) << 3));
#pragma unroll
      for (int n = 0; n < 2; ++n) {
        s[n][f] = zero;
        s[n][f] = __builtin_amdgcn_mfma_f32_16x16x32_bf16(ak0, aq[n][0], s[n][f], 0, 0, 0);
        s[n][f] = __builtin_amdgcn_mfma_f32_16x16x32_bf16(ak1, aq[n][1], s[n][f], 0, 0, 0);
      }
    }
    __builtin_amdgcn_s_setprio(0);

    // mask invalid kv (only last iteration; garbage K rows -> masked here)
    const int kv0 = it * 64;
    if (kv0 + 64 > len) {
#pragma unroll
      for (int f = 0; f < 4; ++f) {
        const int kvb = kv0 + f * 16 + quad * 4;
#pragma unroll
        for (int r = 0; r < 4; ++r)
          if (kvb + r >= len) { s[0][f][r] = NEGV; s[1][f][r] = NEGV; }
      }
    }

    // no-max softmax: p = exp2(s) directly (raw v_exp_f32; exp2(-1e30)=0 exactly);
    // per-lane partial l, cross-quad reduction deferred to epilogue
#pragma unroll
    for (int n = 0; n < 2; ++n) {
      float rs = 0.f;
#pragma unroll
      for (int f = 0; f < 4; ++f)
#pragma unroll
        for (int r = 0; r < 4; ++r) {
          const float p = EXP2F(s[n][f][r]);
          s[n][f][r] = p;
          rs += p;
        }
      l_i[n] += rs;
    }

    // pack P^T (registers) as B-operand: slot (quad,j) <-> kv = g*32 + (j>>2)*16 + quad*4 + (j&3)
    // compiler casts fuse to v_cvt_pk_bf16_f32 (m240: better than hand bit-packing)
    bf16x8 bp[2][2];
#pragma unroll
    for (int n = 0; n < 2; ++n)
#pragma unroll
      for (int g = 0; g < 2; ++g) {
        bf16x8 t;
#pragma unroll
        for (int r = 0; r < 4; ++r) {
          t[r]     = (__bf16)s[n][2 * g][r];
          t[r + 4] = (__bf16)s[n][2 * g + 1][r];
        }
        bp[n][g] = t;
      }

    // O^T += V^T * P^T : A = V^T-frag (m=d), B = P^T (regs). C: row(d)=quad*4+reg, col(q)=c16
    __builtin_amdgcn_s_setprio(1);
#pragma unroll
    for (int m = 0; m < 4; ++m) {
      const int row = m * 16 + c16;
      const int ch = c16 & 7;
      bf16x8 av0 = *(const bf16x8*)(Vt + row * 64 + ((quad ^ ch) << 3));
      bf16x8 av1 = *(const bf16x8*)(Vt + row * 64 + (((4 + quad) ^ ch) << 3));
#pragma unroll
      for (int n = 0; n < 2; ++n) {
        o_acc[n][m] = __builtin_amdgcn_mfma_f32_16x16x32_bf16(av0, bp[n][0], o_acc[n][m], 0, 0, 0);
        o_acc[n][m] = __builtin_amdgcn_mfma_f32_16x16x32_bf16(av1, bp[n][1], o_acc[n][m], 0, 0, 0);
      }
    }
    __builtin_amdgcn_s_setprio(0);
  }

  // epilogue: reduce l across quads, normalize, store bf16.
  // O^T: d = m*16+quad*4+r, q = wave*32+n*16+c16
#pragma unroll
  for (int n = 0; n < 2; ++n) {
    float l = l_i[n];
    l += __shfl_xor(l, 16);
    l += __shfl_xor(l, 32);
    const int q = q0 + wave * 32 + n * 16 + c16;
    if (q < len) {
      const float inv = 1.0f / l;
      const size_t base = (size_t)(seg0 + q) * DMODEL + h * DHEAD;
#pragma unroll
      for (int m = 0; m < 4; ++m) {
        ushort4 pk;
        pk.x = f2bf(o_acc[n][m][0] * inv);
        pk.y = f2bf(o_acc[n][m][1] * inv);
        pk.z = f2bf(o_acc[n][m][2] * inv);
        pk.w = f2bf(o_acc[n][m][3] * inv);
        *(ushort4*)(ob + base + m * 16 + quad * 4) = pk;
      }
    }
  }
}

// ---------------- launch ----------------
extern "C" void kernel_launch(void* const* d_in, const int* in_sizes, int n_in,
                              void* d_out, int out_size, void* d_ws, size_t ws_size,
                              hipStream_t stream)
{
  (void)n_in; (void)out_size; (void)ws_size;
  const float* hs = (const float*)d_in[0];
  const int*   cu = (const int*)d_in[1];
  const float* Wq = (const float*)d_in[2];
  const float* bq = (const float*)d_in[3];
  const float* Wk = (const float*)d_in[4];
  const float* Wv = (const float*)d_in[5];
  const float* bv = (const float*)d_in[6];
  const float* Wo = (const float*)d_in[7];
  const float* bo = (const float*)d_in[8];
  float* out = (float*)d_out;
  const int T  = in_sizes[0] / DMODEL;            // 6000
  const int DD = DMODEL * DMODEL;
  const int nX = T * DMODEL;

  // workspace layout (ushort elements):
  //   [0]      X bf16 [T,D]   (reused as ob after gemm_qkv)
  //   [nX]     W4 bf16 [4][D,D]
  //   [+4DD]   qb [T,D]
  //   [+T*D]   kb [T,D]
  //   [+T*D]   vt [D][NSEG][SPAD]   (last region: attn OOB row reads stay inside ws)
  ushort* ws  = (ushort*)d_ws;
  ushort* X   = ws;
  ushort* W4  = X + (size_t)nX;
  ushort* qb  = W4 + 4 * (size_t)DD;
  ushort* kb  = qb + (size_t)T * DMODEL;
  ushort* vt  = kb + (size_t)T * DMODEL;
  ushort* ob  = X;                                // X dead after gemm_qkv

  const int ncvt = nX + 4 * DD;
  cvt_all<<<(ncvt / 4 + 255) / 256, 256, 0, stream>>>(hs, Wq, Wk, Wv, Wo, ws, nX, DD);

  gemm_qkv<<<dim3(32, (T + BM - 1) / BM), 256, 0, stream>>>(
      X, W4, bq, bv, cu, qb, kb, vt, T);

  attn_fused<<<dim3(NSEG * NHEAD, QT256), 512, 0, stream>>>(qb, kb, vt, ob, cu, T);

  gemm_out<<<dim3(16, (T + BM - 1) / BM), 256, 0, stream>>>(
      ob, W4 + 3 * (size_t)DD, bo, out, T);
}

// Round 6
// 296.618 us; speedup vs baseline: 1.0680x; 1.0039x over previous
//
#include <hip/hip_runtime.h>
#include <stdint.h>
#include <math.h>

#define DMODEL 1280
#define NHEAD  20
#define DHEAD  64
#define NSEG   4
#define MAXS   1500
#define SPAD   1536              // padded per-segment kv length (multiple of 64)
#define TPAD   (NSEG*SPAD)       // 6144
#define QT256  ((MAXS + 255) / 256)  // 6 q-tiles for attention (256 q-rows/block)
#define BM 128
#define BN 128
#define BK 32
#define OBM 64                   // gemm_out tile (2-wave blocks)
#define OBN 128
#define QSCALE 0.18033688011112042f  // 0.125 * log2(e): fold softmax scale+log2e into Q
#define NEGV  -1e30f

typedef float  f32x4  __attribute__((ext_vector_type(4)));
typedef __bf16 bf16x8 __attribute__((ext_vector_type(8)));

#if __has_builtin(__builtin_amdgcn_exp2f)
#define EXP2F(x) __builtin_amdgcn_exp2f(x)
#else
#define EXP2F(x) exp2f(x)
#endif

__device__ __forceinline__ ushort f2bf(float f) {
  union { float f; uint32_t u; } a; a.f = f;
  uint32_t u = a.u;
  u += 0x7FFFu + ((u >> 16) & 1u);   // RNE
  return (ushort)(u >> 16);
}

// async global->LDS, 16B per lane: lane i lands at lds + i*16 (wave-uniform base).
__device__ __forceinline__ void async16(const void* g, void* lds) {
  __builtin_amdgcn_global_load_lds((const __attribute__((address_space(1))) void*)g,
                                   (__attribute__((address_space(3))) void*)lds,
                                   16, 0, 0);
}

// kv permutation within each 32-block of the transposed-V layout:
// stored position p <-> actual offset a, p = ((a>>2)&3)*8 + ((a>>4)&1)*4 + (a&3)
__device__ __forceinline__ int perm32(int a) {
  return ((a >> 2) & 3) * 8 + ((a >> 4) & 1) * 4 + (a & 3);
}

// ---------------- fused fp32 -> bf16 convert: X then 4 weights (adjacent in ws) ----------
// Grid-stride, 2048 blocks, 8 elems (32B read / 16B write) per thread per iter.
// (R5 attribution: the old 13,898-tiny-block version was a latency/generation-churn
// suspect in the ~136 us cvt+out+gap remainder.)
__global__ void __launch_bounds__(256)
cvt_all(const float* __restrict__ hs, const float* __restrict__ Wq,
        const float* __restrict__ Wk, const float* __restrict__ Wv,
        const float* __restrict__ Wo, ushort* __restrict__ dst, int nX, int DD) {
  const int ng = (nX + 4 * DD) >> 3;          // 8-elem granules; nX, DD divisible by 8
  const int stride = gridDim.x * 256;
  for (int g = blockIdx.x * 256 + threadIdx.x; g < ng; g += stride) {
    const int i = g << 3;
    const float* src;
    if (i < nX) {
      src = hs + i;
    } else {
      const int j = i - nX;
      const int z = (j >= DD) + (j >= 2 * DD) + (j >= 3 * DD);
      const float* w = (z == 0) ? Wq : (z == 1) ? Wk : (z == 2) ? Wv : Wo;
      src = w + (j - z * DD);
    }
    const float4 v0 = ((const float4*)src)[0];
    const float4 v1 = ((const float4*)src)[1];
    ushort4 o0, o1;
    o0.x = f2bf(v0.x); o0.y = f2bf(v0.y); o0.z = f2bf(v0.z); o0.w = f2bf(v0.w);
    o1.x = f2bf(v1.x); o1.y = f2bf(v1.y); o1.z = f2bf(v1.z); o1.w = f2bf(v1.w);
    ((ushort4*)(dst + i))[0] = o0;
    ((ushort4*)(dst + i))[1] = o1;
  }
}

// ---------------- GEMM mainloop (C = A[M,K] * W[N,K]^T) ----------------
// (R2-proven structure: 128x128 tile, 2-buffer global_load_lds, ~2.3 blocks/CU)
// LDS tile: 64 super-rows (2 K-rows) x 8 chunks of 16B, chunk pos p' = p ^ (sr&7);
// 128B super-rows + 3-bit XOR measured 0 bank conflicts.
__device__ __forceinline__ void gemm_tile_mainloop(
    const ushort* __restrict__ A, const ushort* __restrict__ W,
    int M, int m0, int n0, ushort* As, ushort* Bs, f32x4 (&acc)[4][4])
{
  const int tid  = threadIdx.x;
  const int wave = tid >> 6, lane = tid & 63;
  const int quad = lane >> 4, c16 = lane & 15;
  const int wr = (wave >> 1) * 64, wc = (wave & 1) * 64;

  // staging slots: M0 = wave*128 + lane, M1 = M0 + 64 (512 slots/tile)
  const int M0 = wave * 128 + lane, M1 = M0 + 64;
  const int sr0 = M0 >> 3, pp0 = M0 & 7, p0 = pp0 ^ (sr0 & 7);
  const int sr1 = M1 >> 3, pp1 = M1 & 7, p1 = pp1 ^ (sr1 & 7);
  const int row0 = sr0 * 2 + (p0 >> 2), kc0 = (p0 & 3) << 3;
  const int row1 = sr1 * 2 + (p1 >> 2), kc1 = (p1 & 3) << 3;
  // no row clamp: OOB rows (m-edge tile) read into the next ws region; results masked at store
  const ushort* Ap0 = A + (size_t)(m0 + row0) * DMODEL + kc0;
  const ushort* Ap1 = A + (size_t)(m0 + row1) * DMODEL + kc1;
  const ushort* Bp0 = W + (size_t)(n0 + row0) * DMODEL + kc0;
  const ushort* Bp1 = W + (size_t)(n0 + row1) * DMODEL + kc1;
  const int o0 = wave * 1024;        // ushort offset of this wave's first 64 slots
  const int o1 = wave * 1024 + 512;
  const int BUF = BM * BK;           // 4096 ushorts per buffer

  // prologue: stage k0 = 0 into buffer 0
  async16(Ap0, As + o0); async16(Ap1, As + o1);
  async16(Bp0, Bs + o0); async16(Bp1, Bs + o1);

  int c = 0;
  for (int k0 = 0; k0 < DMODEL; k0 += BK, c ^= 1) {
    __syncthreads();                 // publishes buf c (drains the staging loads)
    if (k0 + BK < DMODEL) {          // prefetch next tile into buf c^1 (overlaps compute)
      const int kn = k0 + BK;
      const int bo = (c ^ 1) * BUF;
      async16(Ap0 + kn, As + bo + o0); async16(Ap1 + kn, As + bo + o1);
      async16(Bp0 + kn, Bs + bo + o0); async16(Bp1 + kn, Bs + bo + o1);
    }
    const ushort* Ab = As + c * BUF;
    const ushort* Bb = Bs + c * BUF;
    bf16x8 a[4], b[4];
#pragma unroll
    for (int i = 0; i < 4; ++i) {
      const int row = wr + i * 16 + c16;
      const int sr = row >> 1;
      const int off = (sr << 6) + (((((row & 1) << 2) | quad) ^ (sr & 7)) << 3);
      a[i] = *(const bf16x8*)(Ab + off);
    }
#pragma unroll
    for (int j = 0; j < 4; ++j) {
      const int row = wc + j * 16 + c16;
      const int sr = row >> 1;
      const int off = (sr << 6) + (((((row & 1) << 2) | quad) ^ (sr & 7)) << 3);
      b[j] = *(const bf16x8*)(Bb + off);
    }
#pragma unroll
    for (int i = 0; i < 4; ++i)
#pragma unroll
      for (int j = 0; j < 4; ++j)
        acc[i][j] = __builtin_amdgcn_mfma_f32_16x16x32_bf16(a[i], b[j], acc[i][j], 0, 0, 0);
  }
}

// ---------------- fused QKV projection, bf16 out (Q pre-scaled, V written transposed) ------
// grid (32, 47): x = weight-group (z*10 + ntile; stride-8 XCD pinning), y = m-tile
// FUSED (not per-z split): R4 attribution showed split costs ~+20 us; fused is proven 103.
__global__ void __launch_bounds__(256, 4)
gemm_qkv(const ushort* __restrict__ X, const ushort* __restrict__ W4,
         const float* __restrict__ bq, const float* __restrict__ bv,
         const int* __restrict__ cu,
         ushort* __restrict__ qb, ushort* __restrict__ kb, ushort* __restrict__ vt, int M)
{
  __shared__ ushort As[2 * BM * BK], Bs[2 * BN * BK];
  const int wg = blockIdx.x;
  if (wg >= 30) return;
  const int z = wg / 10;
  const int n0 = (wg % 10) * BN;
  const int m0 = blockIdx.y * BM;
  const ushort* W = W4 + (size_t)z * DMODEL * DMODEL;

  f32x4 acc[4][4];
  f32x4 zero = {0.f, 0.f, 0.f, 0.f};
#pragma unroll
  for (int i = 0; i < 4; ++i)
#pragma unroll
    for (int j = 0; j < 4; ++j) acc[i][j] = zero;

  gemm_tile_mainloop(X, W, M, m0, n0, As, Bs, acc);

  const int tid = threadIdx.x, wave = tid >> 6, lane = tid & 63;
  const int quad = lane >> 4, c16 = lane & 15;
  const int wr = (wave >> 1) * 64, wc = (wave & 1) * 64;

  if (z == 2) {
    // V: write directly into transposed + kv-permuted layout vt[D][NSEG][SPAD]
    const int c1 = cu[1], c2 = cu[2], c3 = cu[3];
#pragma unroll
    for (int i = 0; i < 4; ++i) {
      const int t0 = m0 + wr + i * 16 + quad * 4;
      const int s0a = (t0 >= c1) + (t0 >= c2) + (t0 >= c3);
      const int s3a = (t0 + 3 >= c1) + (t0 + 3 >= c2) + (t0 + 3 >= c3);
      const int seg0 = (s0a == 0) ? 0 : (s0a == 1) ? c1 : (s0a == 2) ? c2 : c3;
#pragma unroll
      for (int j = 0; j < 4; ++j) {
        const int cfeat = n0 + wc + j * 16 + c16;
        const float bb = bv[cfeat];
        if (t0 + 3 < M && s0a == s3a) {
          const int s = t0 - seg0;                 // s ≡ t0 (mod 4): boundaries are mult of 4
          const size_t base = (size_t)cfeat * TPAD + (size_t)s0a * SPAD
                            + (size_t)(s & ~31) + perm32(s & 31);
          ushort4 w;
          w.x = f2bf(acc[i][j][0] + bb);
          w.y = f2bf(acc[i][j][1] + bb);
          w.z = f2bf(acc[i][j][2] + bb);
          w.w = f2bf(acc[i][j][3] + bb);
          *(ushort4*)(vt + base) = w;
        } else {
#pragma unroll
          for (int r = 0; r < 4; ++r) {
            const int t = t0 + r;
            if (t < M) {
              const int sb = (t >= c1) + (t >= c2) + (t >= c3);
              const int sg = (sb == 0) ? 0 : (sb == 1) ? c1 : (sb == 2) ? c2 : c3;
              const int s = t - sg;
              vt[(size_t)cfeat * TPAD + (size_t)sb * SPAD + (s & ~31) + perm32(s & 31)]
                  = f2bf(acc[i][j][r] + bb);
            }
          }
        }
      }
    }
  } else {
    ushort* out = (z == 0) ? qb : kb;
    const float* bias = (z == 0) ? bq : (const float*)nullptr;
    const float oscale = (z == 0) ? QSCALE : 1.0f;
#pragma unroll
    for (int i = 0; i < 4; ++i) {
      const int rbase = m0 + wr + i * 16 + quad * 4;
#pragma unroll
      for (int j = 0; j < 4; ++j) {
        const int c = n0 + wc + j * 16 + c16;
        const float bb = bias ? bias[c] : 0.f;
#pragma unroll
        for (int r = 0; r < 4; ++r) {
          const int rr = rbase + r;
          if (rr < M) out[(size_t)rr * DMODEL + c] = f2bf((acc[i][j][r] + bb) * oscale);
        }
      }
    }
  }
}

// ---------------- output projection, fp32 out: 64x128 tile, 2-wave blocks ----------------
// R5 attribution: old (16,47) 4-wave version ran 470 useful blocks = 1.8/CU (latency-
// exposed, big tail). This: grid (10, 94) = 940 blocks x 128 thr, 24 KB LDS -> ~6
// blocks/CU. Per-wave K-step work IDENTICAL to proven mainloop (4 A-frag + 4 B-frag +
// 16 MFMA, same XOR layout, same 2-buffer schedule); only staging decode differs
// (A: 2 slots/thread, B: 4 slots/thread).
__global__ void __launch_bounds__(128, 3)
gemm_out(const ushort* __restrict__ A, const ushort* __restrict__ W,
         const float* __restrict__ bias, float* __restrict__ out, int M)
{
  __shared__ ushort As[2 * OBM * BK], Bs[2 * OBN * BK];   // 8 KB + 16 KB
  const int n0 = blockIdx.x * OBN;
  const int m0 = blockIdx.y * OBM;
  const int tid = threadIdx.x, wave = tid >> 6, lane = tid & 63;
  const int quad = lane >> 4, c16 = lane & 15;

  // staging decode: slot s -> sr=s>>3, p=(s&7)^(sr&7), row=2sr+(p>>2), kc=(p&3)*8
  // A slots: {tid, tid+128} (256 total); B slots: {tid, +128, +256, +384} (512 total)
  int rA[2], kA[2], rB[4], kB[4];
#pragma unroll
  for (int q = 0; q < 2; ++q) {
    const int s = tid + q * 128;
    const int sr = s >> 3, p = (s & 7) ^ (sr & 7);
    rA[q] = sr * 2 + (p >> 2); kA[q] = (p & 3) << 3;
  }
#pragma unroll
  for (int q = 0; q < 4; ++q) {
    const int s = tid + q * 128;
    const int sr = s >> 3, p = (s & 7) ^ (sr & 7);
    rB[q] = sr * 2 + (p >> 2); kB[q] = (p & 3) << 3;
  }
  // OOB m-edge rows (m0+row >= M) read into the next ws region; masked at store
  const ushort* ApS0 = A + (size_t)(m0 + rA[0]) * DMODEL + kA[0];
  const ushort* ApS1 = A + (size_t)(m0 + rA[1]) * DMODEL + kA[1];
  const ushort* BpS0 = W + (size_t)(n0 + rB[0]) * DMODEL + kB[0];
  const ushort* BpS1 = W + (size_t)(n0 + rB[1]) * DMODEL + kB[1];
  const ushort* BpS2 = W + (size_t)(n0 + rB[2]) * DMODEL + kB[2];
  const ushort* BpS3 = W + (size_t)(n0 + rB[3]) * DMODEL + kB[3];
  // wave-uniform LDS bases (slot group q*128 + wave*64; lane lands at +lane*16B)
  const int aO0 = (wave * 64) * 8,       aO1 = (128 + wave * 64) * 8;
  const int bO0 = (wave * 64) * 8,       bO1 = (128 + wave * 64) * 8;
  const int bO2 = (256 + wave * 64) * 8, bO3 = (384 + wave * 64) * 8;
  const int BUFA = OBM * BK;   // 2048 ushorts
  const int BUFB = OBN * BK;   // 4096 ushorts

#define OSTAGE(c, kk) do { \
    ushort* Ad = As + (c) * BUFA; ushort* Bd = Bs + (c) * BUFB; \
    async16(ApS0 + (kk), Ad + aO0); async16(ApS1 + (kk), Ad + aO1); \
    async16(BpS0 + (kk), Bd + bO0); async16(BpS1 + (kk), Bd + bO1); \
    async16(BpS2 + (kk), Bd + bO2); async16(BpS3 + (kk), Bd + bO3); \
  } while (0)

  f32x4 acc[4][4];
  f32x4 zero = {0.f, 0.f, 0.f, 0.f};
#pragma unroll
  for (int i = 0; i < 4; ++i)
#pragma unroll
    for (int j = 0; j < 4; ++j) acc[i][j] = zero;

  OSTAGE(0, 0);
  int c = 0;
  for (int k0 = 0; k0 < DMODEL; k0 += BK, c ^= 1) {
    __syncthreads();                 // publishes buf c
    if (k0 + BK < DMODEL) OSTAGE(c ^ 1, k0 + BK);
    const ushort* Ab = As + c * BUFA;
    const ushort* Bb = Bs + c * BUFB;
    bf16x8 a[4], b[4];
#pragma unroll
    for (int i = 0; i < 4; ++i) {            // A rows 0..63 (shared by both waves)
      const int row = i * 16 + c16;
      const int sr = row >> 1;
      const int off = (sr << 6) + (((((row & 1) << 2) | quad) ^ (sr & 7)) << 3);
      a[i] = *(const bf16x8*)(Ab + off);
    }
#pragma unroll
    for (int j = 0; j < 4; ++j) {            // B rows wave*64 .. wave*64+63
      const int row = wave * 64 + j * 16 + c16;
      const int sr = row >> 1;
      const int off = (sr << 6) + (((((row & 1) << 2) | quad) ^ (sr & 7)) << 3);
      b[j] = *(const bf16x8*)(Bb + off);
    }
#pragma unroll
    for (int i = 0; i < 4; ++i)
#pragma unroll
      for (int j = 0; j < 4; ++j)
        acc[i][j] = __builtin_amdgcn_mfma_f32_16x16x32_bf16(a[i], b[j], acc[i][j], 0, 0, 0);
  }
#undef OSTAGE

#pragma unroll
  for (int i = 0; i < 4; ++i) {
    const int rbase = m0 + i * 16 + quad * 4;
#pragma unroll
    for (int j = 0; j < 4; ++j) {
      const int cc = n0 + wave * 64 + j * 16 + c16;
      const float bb = bias[cc];
#pragma unroll
      for (int r = 0; r < 4; ++r) {
        const int rr = rbase + r;
        if (rr < M) out[(size_t)rr * DMODEL + cc] = acc[i][j][r] + bb;
      }
    }
  }
}

// ---------------- fused flash attention (8-wave, 256 q-rows/block) ----------------
// S^T trick (P stays in registers), no-max softmax, K/V double-buffer in LDS.
// P->bf16 via compiler casts (fuse to v_cvt_pk_bf16_f32, m240).
// LDS = 32 KB total: Q staged in all of it, then recycled as KV dbuf [2][8192 ushorts].
// grid: (NSEG*NHEAD, QT256): x = head-seg (pins all q-tiles of one (b,h) to one XCD)
__global__ void __launch_bounds__(512, 4)
attn_fused(const ushort* __restrict__ qb, const ushort* __restrict__ kb,
           const ushort* __restrict__ vt, ushort* __restrict__ ob,
           const int* __restrict__ cu, int T)
{
  __shared__ ushort SB[16384];     // 32 KB
  const int hs = blockIdx.x;
  const int b = hs / NHEAD, h = hs % NHEAD;
  const int seg0 = cu[b];
  const int len  = cu[b + 1] - seg0;
  const int q0 = blockIdx.y * 256;
  if (q0 >= len) return;
  const int tid = threadIdx.x, wave = tid >> 6, lane = tid & 63;
  const int quad = lane >> 4, c16 = lane & 15;

  // ---- stage Q (256 rows x 64 d = 32KB) into SB, pre-swizzled-global chunks ----
#pragma unroll
  for (int t = 0; t < 4; ++t) {
    const int slot = t * 512 + tid;
    const int r = slot >> 3, k2 = slot & 7;
    const int col = ((k2 ^ (r & 7)) << 3);
    async16(qb + (size_t)(seg0 + q0 + r) * DMODEL + h * DHEAD + col,
            &SB[(t * 512 + wave * 64) * 8]);
  }

  // ---- per-lane K/V staging pointers (512 threads cover 64 rows x 8 chunks) ----
  const int rK = tid >> 3, kK = tid & 7;
  const int colK = ((kK ^ (rK & 7)) << 3);
  const ushort* kp = kb + (size_t)(seg0 + rK) * DMODEL + h * DHEAD + colK;
  const ushort* vp = vt + (size_t)(h * DHEAD + rK) * TPAD + (size_t)b * SPAD + colK;
  const int ldsoff = wave * 512;   // ushort offset of this wave's 64 staging slots

  __syncthreads();   // Q published (drains vmcnt)

  // Q fragments -> registers; SB is dead afterwards (recycled as kv double-buffer)
  bf16x8 aq[2][2];
#pragma unroll
  for (int n = 0; n < 2; ++n)
#pragma unroll
    for (int ks = 0; ks < 2; ++ks) {
      const int row = wave * 32 + n * 16 + c16;
      aq[n][ks] = *(const bf16x8*)(&SB[row * 64 + (((ks * 4 + quad) ^ (c16 & 7)) << 3)]);
    }

  __syncthreads();   // all Q reads complete; SB reusable

  // stage kv tile 0 into buf0 (K at +0, V at +4096 within each 8192-ushort buffer)
  async16(kp, &SB[ldsoff]); async16(vp, &SB[4096 + ldsoff]);
  kp += (size_t)64 * DMODEL; vp += 64;

  float l_i[2] = {0.f, 0.f};
  f32x4 o_acc[2][4];
  f32x4 zero = {0.f, 0.f, 0.f, 0.f};
#pragma unroll
  for (int n = 0; n < 2; ++n)
#pragma unroll
    for (int m = 0; m < 4; ++m) o_acc[n][m] = zero;

  const int niter = (len + 63) >> 6;
  for (int it = 0; it < niter; ++it) {
    __syncthreads();   // publish buf it&1 (drains staging); prior-iter LDS reads done
    const ushort* Kt = &SB[(it & 1) * 8192];
    const ushort* Vt = Kt + 4096;

    // prefetch next kv-tile into the other buffer — overlaps this iteration's compute
    if (it + 1 < niter) {
      ushort* Dst = &SB[((it + 1) & 1) * 8192];
      async16(kp, Dst + ldsoff); async16(vp, Dst + 4096 + ldsoff);
      kp += (size_t)64 * DMODEL; vp += 64;
    }

    // S^T = K * Q^T : A = K-frag (m=kv), B = Q-frag (n=q). C: row(kv)=quad*4+reg, col(q)=c16
    f32x4 s[2][4];
    __builtin_amdgcn_s_setprio(1);
#pragma unroll
    for (int f = 0; f < 4; ++f) {
      const int row = f * 16 + c16;
      const int ch = c16 & 7;
      bf16x8 ak0 = *(const bf16x8*)(Kt + row * 64 + ((quad ^ ch) << 3));
      bf16x8 ak1 = *(const bf16x8*)(Kt + row * 64 + (((4 + quad) ^ ch) << 3));
#pragma unroll
      for (int n = 0; n < 2; ++n) {
        s[n][f] = zero;
        s[n][f] = __builtin_amdgcn_mfma_f32_16x16x32_bf16(ak0, aq[n][0], s[n][f], 0, 0, 0);
        s[n][f] = __builtin_amdgcn_mfma_f32_16x16x32_bf16(ak1, aq[n][1], s[n][f], 0, 0, 0);
      }
    }
    __builtin_amdgcn_s_setprio(0);

    // mask invalid kv (only last iteration; garbage K rows -> masked here)
    const int kv0 = it * 64;
    if (kv0 + 64 > len) {
#pragma unroll
      for (int f = 0; f < 4; ++f) {
        const int kvb = kv0 + f * 16 + quad * 4;
#pragma unroll
        for (int r = 0; r < 4; ++r)
          if (kvb + r >= len) { s[0][f][r] = NEGV; s[1][f][r] = NEGV; }
      }
    }

    // no-max softmax: p = exp2(s) directly (raw v_exp_f32; exp2(-1e30)=0 exactly);
    // per-lane partial l, cross-quad reduction deferred to epilogue
#pragma unroll
    for (int n = 0; n < 2; ++n) {
      float rs = 0.f;
#pragma unroll
      for (int f = 0; f < 4; ++f)
#pragma unroll
        for (int r = 0; r < 4; ++r) {
          const float p = EXP2F(s[n][f][r]);
          s[n][f][r] = p;
          rs += p;
        }
      l_i[n] += rs;
    }

    // pack P^T (registers) as B-operand: slot (quad,j) <-> kv = g*32 + (j>>2)*16 + quad*4 + (j&3)
    bf16x8 bp[2][2];
#pragma unroll
    for (int n = 0; n < 2; ++n)
#pragma unroll
      for (int g = 0; g < 2; ++g) {
        bf16x8 t;
#pragma unroll
        for (int r = 0; r < 4; ++r) {
          t[r]     = (__bf16)s[n][2 * g][r];
          t[r + 4] = (__bf16)s[n][2 * g + 1][r];
        }
        bp[n][g] = t;
      }

    // O^T += V^T * P^T : A = V^T-frag (m=d), B = P^T (regs). C: row(d)=quad*4+reg, col(q)=c16
    __builtin_amdgcn_s_setprio(1);
#pragma unroll
    for (int m = 0; m < 4; ++m) {
      const int row = m * 16 + c16;
      const int ch = c16 & 7;
      bf16x8 av0 = *(const bf16x8*)(Vt + row * 64 + ((quad ^ ch) << 3));
      bf16x8 av1 = *(const bf16x8*)(Vt + row * 64 + (((4 + quad) ^ ch) << 3));
#pragma unroll
      for (int n = 0; n < 2; ++n) {
        o_acc[n][m] = __builtin_amdgcn_mfma_f32_16x16x32_bf16(av0, bp[n][0], o_acc[n][m], 0, 0, 0);
        o_acc[n][m] = __builtin_amdgcn_mfma_f32_16x16x32_bf16(av1, bp[n][1], o_acc[n][m], 0, 0, 0);
      }
    }
    __builtin_amdgcn_s_setprio(0);
  }

  // epilogue: reduce l across quads, normalize, store bf16.
  // O^T: d = m*16+quad*4+r, q = wave*32+n*16+c16
#pragma unroll
  for (int n = 0; n < 2; ++n) {
    float l = l_i[n];
    l += __shfl_xor(l, 16);
    l += __shfl_xor(l, 32);
    const int q = q0 + wave * 32 + n * 16 + c16;
    if (q < len) {
      const float inv = 1.0f / l;
      const size_t base = (size_t)(seg0 + q) * DMODEL + h * DHEAD;
#pragma unroll
      for (int m = 0; m < 4; ++m) {
        ushort4 pk;
        pk.x = f2bf(o_acc[n][m][0] * inv);
        pk.y = f2bf(o_acc[n][m][1] * inv);
        pk.z = f2bf(o_acc[n][m][2] * inv);
        pk.w = f2bf(o_acc[n][m][3] * inv);
        *(ushort4*)(ob + base + m * 16 + quad * 4) = pk;
      }
    }
  }
}

// ---------------- launch ----------------
extern "C" void kernel_launch(void* const* d_in, const int* in_sizes, int n_in,
                              void* d_out, int out_size, void* d_ws, size_t ws_size,
                              hipStream_t stream)
{
  (void)n_in; (void)out_size; (void)ws_size;
  const float* hs = (const float*)d_in[0];
  const int*   cu = (const int*)d_in[1];
  const float* Wq = (const float*)d_in[2];
  const float* bq = (const float*)d_in[3];
  const float* Wk = (const float*)d_in[4];
  const float* Wv = (const float*)d_in[5];
  const float* bv = (const float*)d_in[6];
  const float* Wo = (const float*)d_in[7];
  const float* bo = (const float*)d_in[8];
  float* out = (float*)d_out;
  const int T  = in_sizes[0] / DMODEL;            // 6000
  const int DD = DMODEL * DMODEL;
  const int nX = T * DMODEL;

  // workspace layout (ushort elements):
  //   [0]      X bf16 [T,D]   (reused as ob after gemm_qkv)
  //   [nX]     W4 bf16 [4][D,D]
  //   [+4DD]   qb [T,D]
  //   [+T*D]   kb [T,D]
  //   [+T*D]   vt [D][NSEG][SPAD]   (last region: attn OOB row reads stay inside ws)
  ushort* ws  = (ushort*)d_ws;
  ushort* X   = ws;
  ushort* W4  = X + (size_t)nX;
  ushort* qb  = W4 + 4 * (size_t)DD;
  ushort* kb  = qb + (size_t)T * DMODEL;
  ushort* vt  = kb + (size_t)T * DMODEL;
  ushort* ob  = X;                                // X dead after gemm_qkv

  cvt_all<<<2048, 256, 0, stream>>>(hs, Wq, Wk, Wv, Wo, ws, nX, DD);

  gemm_qkv<<<dim3(32, (T + BM - 1) / BM), 256, 0, stream>>>(
      X, W4, bq, bv, cu, qb, kb, vt, T);

  attn_fused<<<dim3(NSEG * NHEAD, QT256), 512, 0, stream>>>(qb, kb, vt, ob, cu, T);

  gemm_out<<<dim3(10, (T + OBM - 1) / OBM), 128, 0, stream>>>(
      ob, W4 + 3 * (size_t)DD, bo, out, T);
}